// Round 6
// baseline (139.290 us; speedup 1.0000x reference)
//
#include <hip/hip_runtime.h>
#include <math.h>

typedef _Float16 half8 __attribute__((ext_vector_type(8)));
typedef float floatx4 __attribute__((ext_vector_type(4)));

#define SQ3 1.7320508075688772f

// bw layout: [path(4)][t(8)][s(2)][lane(64)][elem(8)] _Float16  (32768 = 64 KiB)
// bw value = W2[k][col] * scale, k = s*32 + (lane>>4)*8 + elem,
// col = path*128 + t*16 + (lane&15), scale = 1/32 (sqrt3 folded into path C)
__global__ __launch_bounds__(256) void prep_w2(const float* __restrict__ W2,
                                               _Float16* __restrict__ bw) {
    int t = blockIdx.x * 256 + threadIdx.x;
    if (t >= 32768) return;
    int i    = t & 7;
    int l    = (t >> 3) & 63;
    int s    = (t >> 9) & 1;
    int tt   = (t >> 10) & 7;
    int path = t >> 13;
    int k   = s * 32 + (l >> 4) * 8 + i;
    int col = path * 128 + tt * 16 + (l & 15);
    float scale = 0.03125f * (path == 2 ? SQ3 : 1.0f);
    bw[t] = (_Float16)(W2[k * 512 + col] * scale);
}

struct Pref {
    float4 xa, xb;
    float psx, psy, psz, pdx, pdy, pdz;
    int di;
};

__device__ __forceinline__ Pref issue_loads(int tile, int E,
        const int* __restrict__ ei, const float* __restrict__ x,
        const float* __restrict__ pos, int tid) {
    Pref p;
    int el = tid >> 2, q = tid & 3;
    int eg = tile * 64 + el;
    int ec = (eg < E) ? eg : (E - 1);
    int si = ei[ec];
    p.di = ei[E + ec];
    const float* xr = x + (size_t)si * 32 + q * 8;
    p.xa = *reinterpret_cast<const float4*>(xr);
    p.xb = *reinterpret_cast<const float4*>(xr + 4);
    const float* ps = pos + (size_t)si * 3;
    const float* pd = pos + (size_t)p.di * 3;
    p.psx = ps[0]; p.psy = ps[1]; p.psz = ps[2];
    p.pdx = pd[0]; p.pdy = pd[1]; p.pdz = pd[2];
    return p;
}

__global__ __launch_bounds__(256, 4) void edge_kernel(
    const float* __restrict__ x, const float* __restrict__ pos,
    const int* __restrict__ ei, const float* __restrict__ W1,
    const _Float16* __restrict__ bw, float* __restrict__ out,
    int E, int ntiles)
{
    __shared__ float sW1[64];
    __shared__ __align__(16) float4 s_geo[64];            // dx,dy,dz,len
    __shared__ int s_dst[2][64];                           // double-buffered
    __shared__ __align__(16) float s_xs[64][12];           // row pad 48B
    __shared__ __align__(16) float s_xvp[3][64][12];       // xv planes, f32
    __shared__ __align__(16) _Float16 s_hA[4][2][64][8];   // MFMA A-frags
    __shared__ __align__(16) _Float16 s_part[2][64][66];   // pad 66 -> no bank conflict

    const int tid  = threadIdx.x;
    const int wave = tid >> 6;     // 0..3 == path A,B,C,D
    const int lane = tid & 63;

    if (tid < 64) sW1[tid] = W1[tid];

    // register-resident B fragments for this wave's path (16 frags = 64 VGPR)
    half8 bfrag[8][2];
    {
        const half8* bsrc = (const half8*)bw;
        #pragma unroll
        for (int t = 0; t < 8; ++t)
            #pragma unroll
            for (int s = 0; s < 2; ++s)
                bfrag[t][s] = bsrc[(size_t)wave * 1024 + (t * 2 + s) * 64 + lane];
    }

    int tile = blockIdx.x;
    if (tile >= ntiles) return;
    Pref p = issue_loads(tile, E, ei, x, pos, tid);
    __syncthreads();   // sW1 visible before first stage A

    int buf = 0;
    for (; tile < ntiles; tile += gridDim.x) {
        // ===== stage A: prefetched regs -> LDS (geo, features, h frags) =====
        {
            int el = tid >> 2, q = tid & 3;
            float ex = p.pdx - p.psx;
            float ey = p.pdy - p.psy;
            float ez = p.pdz - p.psz;
            float len = fmaxf(sqrtf(ex * ex + ey * ey + ez * ez), 1e-8f);
            float inv = 1.0f / len;
            if (q == 0) {
                s_geo[el] = make_float4(ex * inv, ey * inv, ez * inv, len);
                s_dst[buf][el] = p.di;
                *(float4*)&s_xs[el][0] = p.xa;
                *(float4*)&s_xs[el][4] = p.xb;
            } else {
                int fb = (q - 1) * 8;
                float vals[8] = {p.xa.x, p.xa.y, p.xa.z, p.xa.w,
                                 p.xb.x, p.xb.y, p.xb.z, p.xb.w};
                #pragma unroll
                for (int i2 = 0; i2 < 8; ++i2) {
                    int flat = fb + i2;
                    int u  = (flat * 11) >> 5;      // flat/3 for flat<24
                    int ii = flat - 3 * u;
                    s_xvp[ii][el][u] = vals[i2];
                }
            }
            int sub = el >> 4;
            int l   = (q << 4) | (el & 15);
            #pragma unroll
            for (int s = 0; s < 2; ++s) {
                half8 ha;
                #pragma unroll
                for (int i = 0; i < 8; ++i) {
                    float z = len * sW1[s * 32 + q * 8 + i];
                    ha[i] = (_Float16)(z / (1.0f + __expf(-z)));
                }
                *(half8*)&s_hA[sub][s][l][0] = ha;
            }
        }
        __syncthreads();   // bar1: tile's LDS ready

        // ---- prefetch next tile (loads fly during stage B) ----
        int nt = tile + gridDim.x;
        Pref pn;
        if (nt < ntiles) pn = issue_loads(nt, E, ei, x, pos, tid);

        // ===== stage B: 4 subtiles x 16 MFMA per wave + path epilogue =====
        const int wp  = lane & 15;
        const int er0 = (lane >> 4) * 4;
        #pragma unroll
        for (int sub = 0; sub < 4; ++sub) {
            half8 a0 = *(const half8*)&s_hA[sub][0][lane][0];
            half8 a1 = *(const half8*)&s_hA[sub][1][lane][0];
            floatx4 acc[8];
            #pragma unroll
            for (int t = 0; t < 8; ++t) {
                floatx4 z = {0.f, 0.f, 0.f, 0.f};
                z = __builtin_amdgcn_mfma_f32_16x16x32_f16(a0, bfrag[t][0], z, 0, 0, 0);
                acc[t] = __builtin_amdgcn_mfma_f32_16x16x32_f16(a1, bfrag[t][1], z, 0, 0, 0);
            }

            if (wave == 0) {                 // path A: ms = xs . wA
                #pragma unroll
                for (int r = 0; r < 4; ++r) {
                    int e = sub * 16 + er0 + r;
                    float4 x0 = *(const float4*)&s_xs[e][0];
                    float4 x1 = *(const float4*)&s_xs[e][4];
                    float m = x0.x*acc[0][r] + x0.y*acc[1][r] + x0.z*acc[2][r] + x0.w*acc[3][r]
                            + x1.x*acc[4][r] + x1.y*acc[5][r] + x1.z*acc[6][r] + x1.w*acc[7][r];
                    s_part[0][e][wp] = (_Float16)m;
                }
            } else if (wave == 1) {          // path B: ms = (xv.dir) . wB
                #pragma unroll
                for (int r = 0; r < 4; ++r) {
                    int e = sub * 16 + er0 + r;
                    float4 g = s_geo[e];
                    float m = 0.f;
                    #pragma unroll
                    for (int i = 0; i < 3; ++i) {
                        float4 v0 = *(const float4*)&s_xvp[i][e][0];
                        float4 v1 = *(const float4*)&s_xvp[i][e][4];
                        float gi = (i == 0) ? g.x : ((i == 1) ? g.y : g.z);
                        float d = v0.x*acc[0][r] + v0.y*acc[1][r] + v0.z*acc[2][r] + v0.w*acc[3][r]
                                + v1.x*acc[4][r] + v1.y*acc[5][r] + v1.z*acc[6][r] + v1.w*acc[7][r];
                        m += gi * d;
                    }
                    s_part[1][e][wp] = (_Float16)m;
                }
            } else if (wave == 2) {          // path C: mv = (xs.wC) * sqrt3*dir
                #pragma unroll
                for (int r = 0; r < 4; ++r) {
                    int e = sub * 16 + er0 + r;
                    float4 x0 = *(const float4*)&s_xs[e][0];
                    float4 x1 = *(const float4*)&s_xs[e][4];
                    float4 g = s_geo[e];
                    float cw = x0.x*acc[0][r] + x0.y*acc[1][r] + x0.z*acc[2][r] + x0.w*acc[3][r]
                             + x1.x*acc[4][r] + x1.y*acc[5][r] + x1.z*acc[6][r] + x1.w*acc[7][r];
                    s_part[0][e][16 + wp * 3 + 0] = (_Float16)(cw * g.x);
                    s_part[0][e][16 + wp * 3 + 1] = (_Float16)(cw * g.y);
                    s_part[0][e][16 + wp * 3 + 2] = (_Float16)(cw * g.z);
                }
            } else {                         // path D: mv = xv . wD
                #pragma unroll
                for (int r = 0; r < 4; ++r) {
                    int e = sub * 16 + er0 + r;
                    #pragma unroll
                    for (int i = 0; i < 3; ++i) {
                        float4 v0 = *(const float4*)&s_xvp[i][e][0];
                        float4 v1 = *(const float4*)&s_xvp[i][e][4];
                        float mi = v0.x*acc[0][r] + v0.y*acc[1][r] + v0.z*acc[2][r] + v0.w*acc[3][r]
                                 + v1.x*acc[4][r] + v1.y*acc[5][r] + v1.z*acc[6][r] + v1.w*acc[7][r];
                        s_part[1][e][16 + wp * 3 + i] = (_Float16)mi;
                    }
                }
            }
        }
        __syncthreads();   // bar2: partials ready

        // ===== stage C: coalesced atomic scatter, 64 edges =====
        {
            int c = tid & 63;
            int g = tid >> 6;
            #pragma unroll
            for (int k = 0; k < 16; ++k) {
                int e  = g * 16 + k;
                int eg = tile * 64 + e;
                if (eg < E) {
                    float v = (float)s_part[0][e][c] + (float)s_part[1][e][c];
                    atomicAdd(out + (size_t)s_dst[buf][e] * 64 + c, v);
                }
            }
        }
        p = pn;
        buf ^= 1;
    }
}

__global__ __launch_bounds__(256) void node_kernel(
    float* __restrict__ out, const float* __restrict__ Ws,
    const float* __restrict__ Wns, const float* __restrict__ Wg, int N)
{
    int n = blockIdx.x * 256 + threadIdx.x;
    if (n >= N) return;
    float* row = out + (size_t)n * 64;

    float os[16], ov[48];
    #pragma unroll
    for (int q = 0; q < 4; ++q) {
        float4 v = *reinterpret_cast<const float4*>(row + q * 4);
        os[q*4+0]=v.x; os[q*4+1]=v.y; os[q*4+2]=v.z; os[q*4+3]=v.w;
    }
    #pragma unroll
    for (int q = 0; q < 12; ++q) {
        float4 v = *reinterpret_cast<const float4*>(row + 16 + q * 4);
        ov[q*4+0]=v.x; ov[q*4+1]=v.y; ov[q*4+2]=v.z; ov[q*4+3]=v.w;
    }

    float sres[16], gres[16];
    #pragma unroll
    for (int w = 0; w < 16; ++w) {
        float a = 0.f, b = 0.f;
        #pragma unroll
        for (int u = 0; u < 16; ++u) {
            float o_u = os[u];
            a += o_u * Ws[u * 16 + w];
            b += o_u * Wg[u * 16 + w];
        }
        a *= 0.25f; b *= 0.25f;
        sres[w] = a / (1.0f + __expf(-a));
        gres[w] = 1.0f / (1.0f + __expf(-b));
    }

    float gated[48];
    #pragma unroll
    for (int w = 0; w < 16; ++w) {
        float n0 = 0.f, n1 = 0.f, n2 = 0.f;
        #pragma unroll
        for (int u = 0; u < 16; ++u) {
            float wn = Wns[u * 16 + w];
            n0 += ov[u*3+0] * wn;
            n1 += ov[u*3+1] * wn;
            n2 += ov[u*3+2] * wn;
        }
        float gw = gres[w] * 0.25f;
        gated[w*3+0] = n0 * gw;
        gated[w*3+1] = n1 * gw;
        gated[w*3+2] = n2 * gw;
    }

    #pragma unroll
    for (int q = 0; q < 4; ++q) {
        float4 v = make_float4(sres[q*4+0], sres[q*4+1], sres[q*4+2], sres[q*4+3]);
        *reinterpret_cast<float4*>(row + q * 4) = v;
    }
    #pragma unroll
    for (int q = 0; q < 12; ++q) {
        float4 v = make_float4(gated[q*4+0], gated[q*4+1], gated[q*4+2], gated[q*4+3]);
        *reinterpret_cast<float4*>(row + 16 + q * 4) = v;
    }
}

extern "C" void kernel_launch(void* const* d_in, const int* in_sizes, int n_in,
                              void* d_out, int out_size, void* d_ws, size_t ws_size,
                              hipStream_t stream) {
    const float* x   = (const float*)d_in[0];
    const float* pos = (const float*)d_in[1];
    const int*   ei  = (const int*)d_in[2];
    const float* W1  = (const float*)d_in[3];
    const float* W2  = (const float*)d_in[4];
    const float* Ws  = (const float*)d_in[5];
    const float* Wns = (const float*)d_in[6];
    const float* Wg  = (const float*)d_in[7];

    int N = in_sizes[0] / 32;
    int E = in_sizes[2] / 2;
    int ntiles = (E + 63) / 64;
    float* out = (float*)d_out;
    _Float16* bw = (_Float16*)d_ws;

    hipMemsetAsync(out, 0, (size_t)N * 64 * sizeof(float), stream);
    prep_w2<<<128, 256, 0, stream>>>(W2, bw);
    int nblk = ntiles < 1024 ? ntiles : 1024;
    edge_kernel<<<nblk, 256, 0, stream>>>(x, pos, ei, W1, bw, out, E, ntiles);
    node_kernel<<<(N + 255) / 256, 256, 0, stream>>>(out, Ws, Wns, Wg, N);
}

// Round 7
// 115.133 us; speedup vs baseline: 1.2098x; 1.2098x over previous
//
#include <hip/hip_runtime.h>
#include <math.h>

typedef _Float16 half8 __attribute__((ext_vector_type(8)));
typedef float floatx4 __attribute__((ext_vector_type(4)));

#define SQ3 1.7320508075688772f

// bw layout: [path(4)][t(8)][s(2)][lane(64)][elem(8)] _Float16  (32768 = 64 KiB)
// bw value = W2[k][col] * scale, k = s*32 + (lane>>4)*8 + elem,
// col = path*128 + t*16 + (lane&15), scale = 1/32 (sqrt3 folded into path C)
__global__ __launch_bounds__(256) void prep_w2(const float* __restrict__ W2,
                                               _Float16* __restrict__ bw) {
    int t = blockIdx.x * 256 + threadIdx.x;
    if (t >= 32768) return;
    int i    = t & 7;
    int l    = (t >> 3) & 63;
    int s    = (t >> 9) & 1;
    int tt   = (t >> 10) & 7;
    int path = t >> 13;
    int k   = s * 32 + (l >> 4) * 8 + i;
    int col = path * 128 + tt * 16 + (l & 15);
    float scale = 0.03125f * (path == 2 ? SQ3 : 1.0f);
    bw[t] = (_Float16)(W2[k * 512 + col] * scale);
}

struct Pref {
    float4 xa, xb;
    float psx, psy, psz, pdx, pdy, pdz;
    int di;
};

__device__ __forceinline__ Pref issue_loads(int tile, int E,
        const int* __restrict__ ei, const float* __restrict__ x,
        const float* __restrict__ pos, int tid) {
    Pref p;
    int el = tid >> 2, q = tid & 3;
    int eg = tile * 64 + el;
    int ec = (eg < E) ? eg : (E - 1);
    int si = ei[ec];
    p.di = ei[E + ec];
    const float* xr = x + (size_t)si * 32 + q * 8;
    p.xa = *reinterpret_cast<const float4*>(xr);
    p.xb = *reinterpret_cast<const float4*>(xr + 4);
    const float* ps = pos + (size_t)si * 3;
    const float* pd = pos + (size_t)p.di * 3;
    p.psx = ps[0]; p.psy = ps[1]; p.psz = ps[2];
    p.pdx = pd[0]; p.pdy = pd[1]; p.pdz = pd[2];
    return p;
}

__global__ __launch_bounds__(256) void edge_kernel(
    const float* __restrict__ x, const float* __restrict__ pos,
    const int* __restrict__ ei, const float* __restrict__ W1,
    const _Float16* __restrict__ bw, float* __restrict__ out,
    int E, int ntiles)
{
    __shared__ float sW1[64];
    __shared__ __align__(16) float4 s_geo[64];            // dx,dy,dz,len
    __shared__ int s_dst[2][64];                           // double-buffered
    __shared__ __align__(16) float s_xs[64][12];           // row pad 48B
    __shared__ __align__(16) float s_xvp[3][64][12];       // xv planes, f32
    __shared__ __align__(16) _Float16 s_hA[4][2][64][8];   // MFMA A-frags
    __shared__ __align__(16) _Float16 s_part[2][64][66];   // pad 66 -> no bank conflict

    const int tid  = threadIdx.x;
    const int wave = tid >> 6;     // 0..3 == path A,B,C,D
    const int lane = tid & 63;

    if (tid < 64) sW1[tid] = W1[tid];

    // register-resident B fragments for this wave's path (16 frags = 64 VGPR)
    half8 bfrag[8][2];
    {
        const half8* bsrc = (const half8*)bw;
        #pragma unroll
        for (int t = 0; t < 8; ++t)
            #pragma unroll
            for (int s = 0; s < 2; ++s)
                bfrag[t][s] = bsrc[(size_t)wave * 1024 + (t * 2 + s) * 64 + lane];
    }

    int tile = blockIdx.x;
    if (tile >= ntiles) return;
    Pref p = issue_loads(tile, E, ei, x, pos, tid);
    __syncthreads();   // sW1 visible before first stage A

    int buf = 0;
    for (; tile < ntiles; tile += gridDim.x) {
        // ===== stage A: prefetched regs -> LDS (geo, features, h frags) =====
        {
            int el = tid >> 2, q = tid & 3;
            float ex = p.pdx - p.psx;
            float ey = p.pdy - p.psy;
            float ez = p.pdz - p.psz;
            float len = fmaxf(sqrtf(ex * ex + ey * ey + ez * ez), 1e-8f);
            float inv = 1.0f / len;
            if (q == 0) {
                s_geo[el] = make_float4(ex * inv, ey * inv, ez * inv, len);
                s_dst[buf][el] = p.di;
                *(float4*)&s_xs[el][0] = p.xa;
                *(float4*)&s_xs[el][4] = p.xb;
            } else {
                int fb = (q - 1) * 8;
                float vals[8] = {p.xa.x, p.xa.y, p.xa.z, p.xa.w,
                                 p.xb.x, p.xb.y, p.xb.z, p.xb.w};
                #pragma unroll
                for (int i2 = 0; i2 < 8; ++i2) {
                    int flat = fb + i2;
                    int u  = (flat * 11) >> 5;      // flat/3 for flat<24
                    int ii = flat - 3 * u;
                    s_xvp[ii][el][u] = vals[i2];
                }
            }
            int sub = el >> 4;
            int l   = (q << 4) | (el & 15);
            #pragma unroll
            for (int s = 0; s < 2; ++s) {
                half8 ha;
                #pragma unroll
                for (int i = 0; i < 8; ++i) {
                    float z = len * sW1[s * 32 + q * 8 + i];
                    ha[i] = (_Float16)(z / (1.0f + __expf(-z)));
                }
                *(half8*)&s_hA[sub][s][l][0] = ha;
            }
        }
        __syncthreads();   // bar1: tile's LDS ready

        // ---- prefetch next tile (loads fly during stage B) ----
        int nt = tile + gridDim.x;
        Pref pn;
        if (nt < ntiles) pn = issue_loads(nt, E, ei, x, pos, tid);

        // ===== stage B: 4 subtiles x 16 MFMA per wave + path epilogue =====
        const int wp  = lane & 15;
        const int er0 = (lane >> 4) * 4;
        #pragma unroll
        for (int sub = 0; sub < 4; ++sub) {
            half8 a0 = *(const half8*)&s_hA[sub][0][lane][0];
            half8 a1 = *(const half8*)&s_hA[sub][1][lane][0];
            floatx4 acc[8];
            #pragma unroll
            for (int t = 0; t < 8; ++t) {
                floatx4 z = {0.f, 0.f, 0.f, 0.f};
                z = __builtin_amdgcn_mfma_f32_16x16x32_f16(a0, bfrag[t][0], z, 0, 0, 0);
                acc[t] = __builtin_amdgcn_mfma_f32_16x16x32_f16(a1, bfrag[t][1], z, 0, 0, 0);
            }

            if (wave == 0) {                 // path A: ms = xs . wA
                #pragma unroll
                for (int r = 0; r < 4; ++r) {
                    int e = sub * 16 + er0 + r;
                    float4 x0 = *(const float4*)&s_xs[e][0];
                    float4 x1 = *(const float4*)&s_xs[e][4];
                    float m = x0.x*acc[0][r] + x0.y*acc[1][r] + x0.z*acc[2][r] + x0.w*acc[3][r]
                            + x1.x*acc[4][r] + x1.y*acc[5][r] + x1.z*acc[6][r] + x1.w*acc[7][r];
                    s_part[0][e][wp] = (_Float16)m;
                }
            } else if (wave == 1) {          // path B: ms = (xv.dir) . wB
                #pragma unroll
                for (int r = 0; r < 4; ++r) {
                    int e = sub * 16 + er0 + r;
                    float4 g = s_geo[e];
                    float m = 0.f;
                    #pragma unroll
                    for (int i = 0; i < 3; ++i) {
                        float4 v0 = *(const float4*)&s_xvp[i][e][0];
                        float4 v1 = *(const float4*)&s_xvp[i][e][4];
                        float gi = (i == 0) ? g.x : ((i == 1) ? g.y : g.z);
                        float d = v0.x*acc[0][r] + v0.y*acc[1][r] + v0.z*acc[2][r] + v0.w*acc[3][r]
                                + v1.x*acc[4][r] + v1.y*acc[5][r] + v1.z*acc[6][r] + v1.w*acc[7][r];
                        m += gi * d;
                    }
                    s_part[1][e][wp] = (_Float16)m;
                }
            } else if (wave == 2) {          // path C: mv = (xs.wC) * sqrt3*dir
                #pragma unroll
                for (int r = 0; r < 4; ++r) {
                    int e = sub * 16 + er0 + r;
                    float4 x0 = *(const float4*)&s_xs[e][0];
                    float4 x1 = *(const float4*)&s_xs[e][4];
                    float4 g = s_geo[e];
                    float cw = x0.x*acc[0][r] + x0.y*acc[1][r] + x0.z*acc[2][r] + x0.w*acc[3][r]
                             + x1.x*acc[4][r] + x1.y*acc[5][r] + x1.z*acc[6][r] + x1.w*acc[7][r];
                    s_part[0][e][16 + wp * 3 + 0] = (_Float16)(cw * g.x);
                    s_part[0][e][16 + wp * 3 + 1] = (_Float16)(cw * g.y);
                    s_part[0][e][16 + wp * 3 + 2] = (_Float16)(cw * g.z);
                }
            } else {                         // path D: mv = xv . wD
                #pragma unroll
                for (int r = 0; r < 4; ++r) {
                    int e = sub * 16 + er0 + r;
                    #pragma unroll
                    for (int i = 0; i < 3; ++i) {
                        float4 v0 = *(const float4*)&s_xvp[i][e][0];
                        float4 v1 = *(const float4*)&s_xvp[i][e][4];
                        float mi = v0.x*acc[0][r] + v0.y*acc[1][r] + v0.z*acc[2][r] + v0.w*acc[3][r]
                                 + v1.x*acc[4][r] + v1.y*acc[5][r] + v1.z*acc[6][r] + v1.w*acc[7][r];
                        s_part[1][e][16 + wp * 3 + i] = (_Float16)mi;
                    }
                }
            }
        }
        __syncthreads();   // bar2: partials ready

        // ===== stage C: coalesced atomic scatter, 64 edges =====
        {
            int c = tid & 63;
            int g = tid >> 6;
            #pragma unroll
            for (int k = 0; k < 16; ++k) {
                int e  = g * 16 + k;
                int eg = tile * 64 + e;
                if (eg < E) {
                    float v = (float)s_part[0][e][c] + (float)s_part[1][e][c];
                    atomicAdd(out + (size_t)s_dst[buf][e] * 64 + c, v);
                }
            }
        }
        p = pn;
        buf ^= 1;
    }
}

__global__ __launch_bounds__(256) void node_kernel(
    float* __restrict__ out, const float* __restrict__ Ws,
    const float* __restrict__ Wns, const float* __restrict__ Wg, int N)
{
    int n = blockIdx.x * 256 + threadIdx.x;
    if (n >= N) return;
    float* row = out + (size_t)n * 64;

    float os[16], ov[48];
    #pragma unroll
    for (int q = 0; q < 4; ++q) {
        float4 v = *reinterpret_cast<const float4*>(row + q * 4);
        os[q*4+0]=v.x; os[q*4+1]=v.y; os[q*4+2]=v.z; os[q*4+3]=v.w;
    }
    #pragma unroll
    for (int q = 0; q < 12; ++q) {
        float4 v = *reinterpret_cast<const float4*>(row + 16 + q * 4);
        ov[q*4+0]=v.x; ov[q*4+1]=v.y; ov[q*4+2]=v.z; ov[q*4+3]=v.w;
    }

    float sres[16], gres[16];
    #pragma unroll
    for (int w = 0; w < 16; ++w) {
        float a = 0.f, b = 0.f;
        #pragma unroll
        for (int u = 0; u < 16; ++u) {
            float o_u = os[u];
            a += o_u * Ws[u * 16 + w];
            b += o_u * Wg[u * 16 + w];
        }
        a *= 0.25f; b *= 0.25f;
        sres[w] = a / (1.0f + __expf(-a));
        gres[w] = 1.0f / (1.0f + __expf(-b));
    }

    float gated[48];
    #pragma unroll
    for (int w = 0; w < 16; ++w) {
        float n0 = 0.f, n1 = 0.f, n2 = 0.f;
        #pragma unroll
        for (int u = 0; u < 16; ++u) {
            float wn = Wns[u * 16 + w];
            n0 += ov[u*3+0] * wn;
            n1 += ov[u*3+1] * wn;
            n2 += ov[u*3+2] * wn;
        }
        float gw = gres[w] * 0.25f;
        gated[w*3+0] = n0 * gw;
        gated[w*3+1] = n1 * gw;
        gated[w*3+2] = n2 * gw;
    }

    #pragma unroll
    for (int q = 0; q < 4; ++q) {
        float4 v = make_float4(sres[q*4+0], sres[q*4+1], sres[q*4+2], sres[q*4+3]);
        *reinterpret_cast<float4*>(row + q * 4) = v;
    }
    #pragma unroll
    for (int q = 0; q < 12; ++q) {
        float4 v = make_float4(gated[q*4+0], gated[q*4+1], gated[q*4+2], gated[q*4+3]);
        *reinterpret_cast<float4*>(row + 16 + q * 4) = v;
    }
}

extern "C" void kernel_launch(void* const* d_in, const int* in_sizes, int n_in,
                              void* d_out, int out_size, void* d_ws, size_t ws_size,
                              hipStream_t stream) {
    const float* x   = (const float*)d_in[0];
    const float* pos = (const float*)d_in[1];
    const int*   ei  = (const int*)d_in[2];
    const float* W1  = (const float*)d_in[3];
    const float* W2  = (const float*)d_in[4];
    const float* Ws  = (const float*)d_in[5];
    const float* Wns = (const float*)d_in[6];
    const float* Wg  = (const float*)d_in[7];

    int N = in_sizes[0] / 32;
    int E = in_sizes[2] / 2;
    int ntiles = (E + 63) / 64;
    float* out = (float*)d_out;
    _Float16* bw = (_Float16*)d_ws;

    hipMemsetAsync(out, 0, (size_t)N * 64 * sizeof(float), stream);
    prep_w2<<<128, 256, 0, stream>>>(W2, bw);
    int nblk = ntiles < 1024 ? ntiles : 1024;
    edge_kernel<<<nblk, 256, 0, stream>>>(x, pos, ei, W1, bw, out, E, ntiles);
    node_kernel<<<(N + 255) / 256, 256, 0, stream>>>(out, Ws, Wns, Wg, N);
}

// Round 8
// 107.751 us; speedup vs baseline: 1.2927x; 1.0685x over previous
//
#include <hip/hip_runtime.h>
#include <math.h>

typedef _Float16 half8 __attribute__((ext_vector_type(8)));
typedef float floatx4 __attribute__((ext_vector_type(4)));

#define SQ3 1.7320508075688772f

// bw layout: [path(4)][t(8)][s(2)][lane(64)][elem(8)] _Float16  (32768 = 64 KiB)
// bw value = W2[k][col] * scale, k = s*32 + (lane>>4)*8 + elem,
// col = path*128 + t*16 + (lane&15), scale = 1/32 (sqrt3 folded into path C)
__global__ __launch_bounds__(256) void prep_w2(const float* __restrict__ W2,
                                               _Float16* __restrict__ bw) {
    int t = blockIdx.x * 256 + threadIdx.x;
    if (t >= 32768) return;
    int i    = t & 7;
    int l    = (t >> 3) & 63;
    int s    = (t >> 9) & 1;
    int tt   = (t >> 10) & 7;
    int path = t >> 13;
    int k   = s * 32 + (l >> 4) * 8 + i;
    int col = path * 128 + tt * 16 + (l & 15);
    float scale = 0.03125f * (path == 2 ? SQ3 : 1.0f);
    bw[t] = (_Float16)(W2[k * 512 + col] * scale);
}

struct Pref {
    float4 xa;
    float psx, psy, psz, pdx, pdy, pdz;
    int di;
};

__device__ __forceinline__ Pref issue_loads(int tile, int E,
        const int* __restrict__ ei, const float* __restrict__ x,
        const float* __restrict__ pos, int tid) {
    Pref p;
    int el = tid >> 3, q = tid & 7;
    int eg = tile * 64 + el;
    int ec = (eg < E) ? eg : (E - 1);
    int si = ei[ec];
    p.di = ei[E + ec];
    p.xa = *reinterpret_cast<const float4*>(x + (size_t)si * 32 + q * 4);
    const float* ps = pos + (size_t)si * 3;
    const float* pd = pos + (size_t)p.di * 3;
    p.psx = ps[0]; p.psy = ps[1]; p.psz = ps[2];
    p.pdx = pd[0]; p.pdy = pd[1]; p.pdz = pd[2];
    return p;
}

// 512 threads = 8 waves = (path 0..3) x (u-half 0..1)
__global__ __launch_bounds__(512, 4) void edge_kernel(
    const float* __restrict__ x, const float* __restrict__ pos,
    const int* __restrict__ ei, const float* __restrict__ W1,
    const _Float16* __restrict__ bw, float* __restrict__ out,
    int E, int ntiles)
{
    __shared__ float sW1[64];
    __shared__ __align__(16) float4 s_geo[64];            // dx,dy,dz,len
    __shared__ int s_dst[2][64];                           // double-buffered
    __shared__ __align__(16) float s_xs[64][12];           // row pad 48B
    __shared__ __align__(16) float s_xvp[3][64][12];       // xv planes, f32
    __shared__ __align__(16) _Float16 s_hA[4][2][64][8];   // MFMA A-frags
    __shared__ __align__(16) _Float16 s_part[4][64][66];   // [A0|A1|B0|B1 group]

    const int tid  = threadIdx.x;
    const int wave = tid >> 6;
    const int path = wave >> 1;    // 0..3 == A,B,C,D
    const int th   = wave & 1;     // u-half: u in [th*4, th*4+4)
    const int lane = tid & 63;
    const int ub   = th * 4;

    if (tid < 64) sW1[tid] = W1[tid];

    // register-resident B fragments: this wave's path + u-half (8 frags = 32 VGPR)
    half8 bfrag[4][2];
    {
        const half8* bsrc = (const half8*)bw;
        #pragma unroll
        for (int tt = 0; tt < 4; ++tt)
            #pragma unroll
            for (int s = 0; s < 2; ++s)
                bfrag[tt][s] = bsrc[(size_t)path * 1024 + ((ub + tt) * 2 + s) * 64 + lane];
    }

    int tile = blockIdx.x;
    if (tile >= ntiles) return;
    Pref p = issue_loads(tile, E, ei, x, pos, tid);
    __syncthreads();   // sW1 visible before first stage A

    int buf = 0;
    for (; tile < ntiles; tile += gridDim.x) {
        // ===== stage A: prefetched regs -> LDS (geo, features, h frags) =====
        {
            int el = tid >> 3, q = tid & 7;
            float ex = p.pdx - p.psx;
            float ey = p.pdy - p.psy;
            float ez = p.pdz - p.psz;
            float len = fmaxf(sqrtf(ex * ex + ey * ey + ez * ez), 1e-8f);
            float inv = 1.0f / len;
            if (q == 0) {
                s_geo[el] = make_float4(ex * inv, ey * inv, ez * inv, len);
                s_dst[buf][el] = p.di;
            }
            if (q < 2) {
                *(float4*)&s_xs[el][q * 4] = p.xa;
            } else {
                float vals[4] = {p.xa.x, p.xa.y, p.xa.z, p.xa.w};
                #pragma unroll
                for (int j = 0; j < 4; ++j) {
                    int flat = (q - 2) * 4 + j;      // 0..23
                    int u  = (flat * 11) >> 5;       // flat/3
                    int ii = flat - 3 * u;
                    s_xvp[ii][el][u] = vals[j];
                }
            }
            // h A-fragment: thread (el, q) -> slot (sub=el>>4, s=q>>2, l=(q&3)*16+(el&15))
            int s  = q >> 2, kg = q & 3;
            int sub = el >> 4;
            int l   = kg * 16 + (el & 15);
            half8 ha;
            #pragma unroll
            for (int i = 0; i < 8; ++i) {
                float z = len * sW1[s * 32 + kg * 8 + i];
                ha[i] = (_Float16)(z / (1.0f + __expf(-z)));
            }
            *(half8*)&s_hA[sub][s][l][0] = ha;
        }
        __syncthreads();   // bar1: tile's LDS ready

        // ---- prefetch next tile (loads fly during stage B) ----
        int nt = tile + gridDim.x;
        Pref pn;
        if (nt < ntiles) pn = issue_loads(nt, E, ei, x, pos, tid);

        // ===== stage B: 4 subtiles x 8 MFMA per wave + half-epilogue =====
        const int wp  = lane & 15;
        const int er0 = (lane >> 4) * 4;
        #pragma unroll
        for (int sub = 0; sub < 4; ++sub) {
            half8 a0 = *(const half8*)&s_hA[sub][0][lane][0];
            half8 a1 = *(const half8*)&s_hA[sub][1][lane][0];
            floatx4 acc[4];
            #pragma unroll
            for (int tt = 0; tt < 4; ++tt) {
                floatx4 z = {0.f, 0.f, 0.f, 0.f};
                z = __builtin_amdgcn_mfma_f32_16x16x32_f16(a0, bfrag[tt][0], z, 0, 0, 0);
                acc[tt] = __builtin_amdgcn_mfma_f32_16x16x32_f16(a1, bfrag[tt][1], z, 0, 0, 0);
            }

            if (path == 0) {                 // A: ms(half) = xs[ub..ub+3] . wA
                #pragma unroll
                for (int r = 0; r < 4; ++r) {
                    int e = sub * 16 + er0 + r;
                    float4 x0 = *(const float4*)&s_xs[e][ub];
                    float m = x0.x*acc[0][r] + x0.y*acc[1][r] + x0.z*acc[2][r] + x0.w*acc[3][r];
                    s_part[th][e][wp] = (_Float16)m;
                }
            } else if (path == 1) {          // B: ms(half) = (xv.dir)[ub..] . wB
                #pragma unroll
                for (int r = 0; r < 4; ++r) {
                    int e = sub * 16 + er0 + r;
                    float4 g = s_geo[e];
                    float4 v0 = *(const float4*)&s_xvp[0][e][ub];
                    float4 v1 = *(const float4*)&s_xvp[1][e][ub];
                    float4 v2 = *(const float4*)&s_xvp[2][e][ub];
                    float d0 = v0.x*acc[0][r] + v0.y*acc[1][r] + v0.z*acc[2][r] + v0.w*acc[3][r];
                    float d1 = v1.x*acc[0][r] + v1.y*acc[1][r] + v1.z*acc[2][r] + v1.w*acc[3][r];
                    float d2 = v2.x*acc[0][r] + v2.y*acc[1][r] + v2.z*acc[2][r] + v2.w*acc[3][r];
                    s_part[2 + th][e][wp] = (_Float16)(g.x*d0 + g.y*d1 + g.z*d2);
                }
            } else if (path == 2) {          // C: mv(half) = (xs.wC) * sqrt3*dir
                #pragma unroll
                for (int r = 0; r < 4; ++r) {
                    int e = sub * 16 + er0 + r;
                    float4 x0 = *(const float4*)&s_xs[e][ub];
                    float4 g = s_geo[e];
                    float cw = x0.x*acc[0][r] + x0.y*acc[1][r] + x0.z*acc[2][r] + x0.w*acc[3][r];
                    s_part[th][e][16 + wp * 3 + 0] = (_Float16)(cw * g.x);
                    s_part[th][e][16 + wp * 3 + 1] = (_Float16)(cw * g.y);
                    s_part[th][e][16 + wp * 3 + 2] = (_Float16)(cw * g.z);
                }
            } else {                         // D: mv(half) = xv[ub..] . wD
                #pragma unroll
                for (int r = 0; r < 4; ++r) {
                    int e = sub * 16 + er0 + r;
                    #pragma unroll
                    for (int i = 0; i < 3; ++i) {
                        float4 v0 = *(const float4*)&s_xvp[i][e][ub];
                        float mi = v0.x*acc[0][r] + v0.y*acc[1][r] + v0.z*acc[2][r] + v0.w*acc[3][r];
                        s_part[2 + th][e][16 + wp * 3 + i] = (_Float16)mi;
                    }
                }
            }
        }
        __syncthreads();   // bar2: partials ready

        // ===== stage C: sum 4 partials, coalesced atomic scatter =====
        {
            int c = tid & 63;
            int g = tid >> 6;
            #pragma unroll
            for (int k = 0; k < 8; ++k) {
                int e  = g * 8 + k;
                int eg = tile * 64 + e;
                if (eg < E) {
                    float v = (float)s_part[0][e][c] + (float)s_part[1][e][c]
                            + (float)s_part[2][e][c] + (float)s_part[3][e][c];
                    atomicAdd(out + (size_t)s_dst[buf][e] * 64 + c, v);
                }
            }
        }
        p = pn;
        buf ^= 1;
    }
}

__global__ __launch_bounds__(256) void node_kernel(
    float* __restrict__ out, const float* __restrict__ Ws,
    const float* __restrict__ Wns, const float* __restrict__ Wg, int N)
{
    int n = blockIdx.x * 256 + threadIdx.x;
    if (n >= N) return;
    float* row = out + (size_t)n * 64;

    float os[16], ov[48];
    #pragma unroll
    for (int q = 0; q < 4; ++q) {
        float4 v = *reinterpret_cast<const float4*>(row + q * 4);
        os[q*4+0]=v.x; os[q*4+1]=v.y; os[q*4+2]=v.z; os[q*4+3]=v.w;
    }
    #pragma unroll
    for (int q = 0; q < 12; ++q) {
        float4 v = *reinterpret_cast<const float4*>(row + 16 + q * 4);
        ov[q*4+0]=v.x; ov[q*4+1]=v.y; ov[q*4+2]=v.z; ov[q*4+3]=v.w;
    }

    float sres[16], gres[16];
    #pragma unroll
    for (int w = 0; w < 16; ++w) {
        float a = 0.f, b = 0.f;
        #pragma unroll
        for (int u = 0; u < 16; ++u) {
            float o_u = os[u];
            a += o_u * Ws[u * 16 + w];
            b += o_u * Wg[u * 16 + w];
        }
        a *= 0.25f; b *= 0.25f;
        sres[w] = a / (1.0f + __expf(-a));
        gres[w] = 1.0f / (1.0f + __expf(-b));
    }

    float gated[48];
    #pragma unroll
    for (int w = 0; w < 16; ++w) {
        float n0 = 0.f, n1 = 0.f, n2 = 0.f;
        #pragma unroll
        for (int u = 0; u < 16; ++u) {
            float wn = Wns[u * 16 + w];
            n0 += ov[u*3+0] * wn;
            n1 += ov[u*3+1] * wn;
            n2 += ov[u*3+2] * wn;
        }
        float gw = gres[w] * 0.25f;
        gated[w*3+0] = n0 * gw;
        gated[w*3+1] = n1 * gw;
        gated[w*3+2] = n2 * gw;
    }

    #pragma unroll
    for (int q = 0; q < 4; ++q) {
        float4 v = make_float4(sres[q*4+0], sres[q*4+1], sres[q*4+2], sres[q*4+3]);
        *reinterpret_cast<float4*>(row + q * 4) = v;
    }
    #pragma unroll
    for (int q = 0; q < 12; ++q) {
        float4 v = make_float4(gated[q*4+0], gated[q*4+1], gated[q*4+2], gated[q*4+3]);
        *reinterpret_cast<float4*>(row + 16 + q * 4) = v;
    }
}

extern "C" void kernel_launch(void* const* d_in, const int* in_sizes, int n_in,
                              void* d_out, int out_size, void* d_ws, size_t ws_size,
                              hipStream_t stream) {
    const float* x   = (const float*)d_in[0];
    const float* pos = (const float*)d_in[1];
    const int*   ei  = (const int*)d_in[2];
    const float* W1  = (const float*)d_in[3];
    const float* W2  = (const float*)d_in[4];
    const float* Ws  = (const float*)d_in[5];
    const float* Wns = (const float*)d_in[6];
    const float* Wg  = (const float*)d_in[7];

    int N = in_sizes[0] / 32;
    int E = in_sizes[2] / 2;
    int ntiles = (E + 63) / 64;
    float* out = (float*)d_out;
    _Float16* bw = (_Float16*)d_ws;

    hipMemsetAsync(out, 0, (size_t)N * 64 * sizeof(float), stream);
    prep_w2<<<128, 256, 0, stream>>>(W2, bw);
    int nblk = ntiles < 512 ? ntiles : 512;
    edge_kernel<<<nblk, 512, 0, stream>>>(x, pos, ei, W1, bw, out, E, ntiles);
    node_kernel<<<(N + 255) / 256, 256, 0, stream>>>(out, Ws, Wns, Wg, N);
}